// Round 5
// baseline (755.175 us; speedup 1.0000x reference)
//
#include <hip/hip_runtime.h>

#define HA 256
#define WA 256
#define HB 128
#define WB 128
#define PA 48
#define PB 48
#define PP 96
#define MM 32
#define NPIXA (HA*WA)   // 65536
#define NPIXB (HB*WB)   // 16384

__device__ __forceinline__ float gelu_f(float x) {
    float z = 0.7978845608028654f * (x + 0.044715f * x * x * x);
    float e = __expf(2.0f * z);
    return x - x / (e + 1.0f);
}

// ---------------- tables + encoder fused ----------------
__global__ __launch_bounds__(256) void k_pre(
        float* tfxAT, float* tfyA, float* tiyA,
        float* tfxBT, float* tfyB, float* tixB, float* tiyB,
        const float* u_a, const float* x_a, const float* u_b, const float* x_b,
        const float* wa, const float* ba, const float* wb, const float* bb,
        float* UA, float* UB) {
    const float TWO_PI = 6.28318530717958647692f;
    int bid = blockIdx.x;
    if (bid < 48) {
        int t = bid * 256 + threadIdx.x;
        if (t < MM * WA) {
            int k = t / WA, x = t - k * WA;
            int m = (k * x) & (WA - 1);
            float ang = TWO_PI * (float)m / (float)WA;
            float s, c; __sincosf(ang, &s, &c);
            float sc = 1.0f / (float)(HA * WA);
            tfxAT[(x*MM + k)*2]   = c * sc;
            tfxAT[(x*MM + k)*2+1] = -s * sc;
            int ky = k - 16;
            int my = (ky * x) & (HA - 1);
            float angy = TWO_PI * (float)my / (float)HA;
            float sy, cy; __sincosf(angy, &sy, &cy);
            tfyA[2*t] = cy; tfyA[2*t+1] = -sy;
            tiyA[2*t] = cy; tiyA[2*t+1] = sy;
        } else if (t < MM * WA + MM * WB) {
            int t2 = t - MM * WA;
            int k = t2 / WB, x = t2 - k * WB;
            int m = (k * x) & (WB - 1);
            float ang = TWO_PI * (float)m / (float)WB;
            float s, c; __sincosf(ang, &s, &c);
            float sc = 1.0f / (float)(HB * WB);
            tfxBT[(x*MM + k)*2]   = c * sc;
            tfxBT[(x*MM + k)*2+1] = -s * sc;
            float wgt = (k == 0) ? 1.0f : 2.0f;
            tixB[2*t2] = wgt * c; tixB[2*t2+1] = wgt * s;
            int ky = k - 16;
            int my = (ky * x) & (HB - 1);
            float angy = TWO_PI * (float)my / (float)HB;
            float sy, cy; __sincosf(angy, &sy, &cy);
            tfyB[2*t2] = cy; tfyB[2*t2+1] = -sy;
            tiyB[2*t2] = cy; tiyB[2*t2+1] = sy;
        }
    } else {
        int eb = bid - 48;
        int o = eb / 320;
        int chunk = eb - o * 320;
        if (chunk < 256) {
            int pix = chunk * 256 + threadIdx.x;
            UA[(size_t)o*NPIXA + pix] = wa[o*3+0]*x_a[pix] + wa[o*3+1]*x_a[NPIXA+pix]
                                      + wa[o*3+2]*u_a[pix] + ba[o];
        } else {
            int pix = (chunk - 256) * 256 + threadIdx.x;
            UB[(size_t)o*NPIXB + pix] = wb[o*3+0]*x_b[pix] + wb[o*3+1]*x_b[NPIXB+pix]
                                      + wb[o*3+2]*u_b[pix] + bb[o];
        }
    }
}

// ---------------- forward DFT along x: register-blocked, conflict-free LDS ----------------
// thread = (kx-quad, row); block = 32 rows; LDS rows padded +4 floats.
__global__ __launch_bounds__(256) void k_fwd_x(
        const float* __restrict__ UA, const float* __restrict__ UB,
        float2* __restrict__ FA, float2* __restrict__ FB,
        const float* __restrict__ tfxAT, const float* __restrict__ tfxBT) {
    extern __shared__ float ls[];
    int bid = blockIdx.x;
    const float* U; float2* F; const float2* tT; int N;
    const int NBA = PA * HA / 32;   // 384
    if (bid < NBA) { U = UA; F = FA; tT = (const float2*)tfxAT; N = WA; }
    else { bid -= NBA; U = UB; F = FB; tT = (const float2*)tfxBT; N = WB; }
    int r0 = bid * 32;
    int NP = N + 4;
    int nq = N >> 2;
    const float4* src = (const float4*)(U + (size_t)r0 * N);
    for (int i = threadIdx.x; i < 32 * nq; i += 256) {
        int r = i / nq, xq = i - r * nq;
        *(float4*)(ls + r * NP + xq * 4) = src[(size_t)r * nq + xq];
    }
    __syncthreads();
    int kx0 = (threadIdx.x & 7) * 4;
    int r = threadIdx.x >> 3;
    const float* urow = ls + r * NP;
    float ar0=0,ai0=0,ar1=0,ai1=0,ar2=0,ai2=0,ar3=0,ai3=0;
    #pragma unroll 2
    for (int x = 0; x < N; x += 4) {
        float4 u = *(const float4*)(urow + x);
        const float* tb = (const float*)(tT + (size_t)x * MM + kx0);
        #pragma unroll
        for (int i = 0; i < 4; ++i) {
            float uv = (i==0)?u.x:((i==1)?u.y:((i==2)?u.z:u.w));
            float4 t01 = *(const float4*)(tb + i*64);
            float4 t23 = *(const float4*)(tb + i*64 + 4);
            ar0 += uv*t01.x; ai0 += uv*t01.y;
            ar1 += uv*t01.z; ai1 += uv*t01.w;
            ar2 += uv*t23.x; ai2 += uv*t23.y;
            ar3 += uv*t23.z; ai3 += uv*t23.w;
        }
    }
    float2* Fr = F + (size_t)(r0 + r) * MM + kx0;
    Fr[0] = make_float2(ar0, ai0);
    Fr[1] = make_float2(ar1, ai1);
    Fr[2] = make_float2(ar2, ai2);
    Fr[3] = make_float2(ar3, ai3);
}

// ---------------- forward DFT along y ----------------
__global__ __launch_bounds__(256) void k_fwd_y(
        const float2* __restrict__ FA, const float2* __restrict__ FB, float2* CIN,
        const float* __restrict__ tfyA, const float* __restrict__ tfyB) {
    int bid = blockIdx.x;
    const float2* F; const float2* tab; int Ny, pbase;
    if (bid < PA*4) { F = FA; tab = (const float2*)tfyA; Ny = HA; pbase = 0; }
    else { bid -= PA*4; F = FB; tab = (const float2*)tfyB; Ny = HB; pbase = PA; }
    int c = bid >> 2;
    int j = (bid & 3) * 8 + (threadIdx.x >> 5);
    int kx = threadIdx.x & 31;
    float re = 0.f, im = 0.f;
    const float2* fr = F + (size_t)c * Ny * MM + kx;
    const float2* tj = tab + j * Ny;
    #pragma unroll 4
    for (int y = 0; y < Ny; ++y) {
        float2 f = fr[y * MM];
        float2 t = tj[y];
        re += f.x*t.x - f.y*t.y;
        im += f.x*t.y + f.y*t.x;
    }
    CIN[((pbase + c)*MM + j)*MM + kx] = make_float2(re, im);
}

// ---------------- spectral channel mix: unsplit, deep unroll ----------------
__global__ __launch_bounds__(256) void k_spectral(
        const float* __restrict__ Wre, const float* __restrict__ Wim,
        const float2* __restrict__ CIN, float2* __restrict__ COUT) {
    int t = blockIdx.x * 256 + threadIdx.x;
    int p = t >> 10;
    int mode = t & 1023;
    const float* wr = Wre + (size_t)p * PP * 1024 + mode;
    const float* wi = Wim + (size_t)p * PP * 1024 + mode;
    float re = 0.f, im = 0.f;
    #pragma unroll 8
    for (int q = 0; q < PP; ++q) {
        float a = wr[(size_t)q << 10];
        float b = wi[(size_t)q << 10];
        float2 cv = CIN[(q << 10) + mode];
        re += a*cv.x - b*cv.y;
        im += a*cv.y + b*cv.x;
    }
    COUT[t] = make_float2(re, im);
}

// ---------------- fused inverse: A = inv_y + inv_x + conv1x1 x2 + resid -> UA
//                  B = inv_y + inv_x -> SB ----------------
__global__ __launch_bounds__(256) void k_inv(
        const float2* __restrict__ COUT, float* __restrict__ UA,
        float* __restrict__ SB,
        const float* __restrict__ tiyA, const float* __restrict__ tiyB,
        const float* __restrict__ tixB,
        const float* __restrict__ w1, const float* __restrict__ b1,
        const float* __restrict__ w2, const float* __restrict__ b2) {
    __shared__ float sm[6144 + 6144 + 2304 + 48 + 64];
    int t = threadIdx.x;
    if (blockIdx.x < 512) {
        // ---- A path: block = (row y, x-half) ----
        float* buf0 = sm;
        float2* Dw  = (float2*)sm;
        float* sl   = sm + 6144;
        float* wl   = sm + 12288;
        float* bl   = sm + 14592;
        float2* tl  = (float2*)(sm + 14640);
        int y  = blockIdx.x >> 1;
        int xh = (blockIdx.x & 1) << 7;
        if (t < 32) tl[t] = ((const float2*)tiyA)[t*HA + y];
        for (int idx = t; idx < 2304; idx += 256) {
            int o = idx % 48, i = idx / 48;
            wl[i*48 + o] = w1[o*48 + i];
        }
        if (t < 48) bl[t] = b1[t];
        __syncthreads();
        // phase 0: D(c,kx) = sum_j COUT(c,j,kx) * Tiy(j,y), c2r weight folded
        {
            int kx = t & 31, c0 = t >> 5;    // c = c0 + 8k, k=0..5
            float re[6] = {0,0,0,0,0,0}, im[6] = {0,0,0,0,0,0};
            for (int j = 0; j < 32; ++j) {
                float2 ty = tl[j];
                #pragma unroll
                for (int k = 0; k < 6; ++k) {
                    float2 w = COUT[((c0 + 8*k)*32 + j)*32 + kx];
                    re[k] += w.x*ty.x - w.y*ty.y;
                    im[k] += w.x*ty.y + w.y*ty.x;
                }
            }
            float wgt = (kx == 0) ? 1.0f : 2.0f;
            #pragma unroll
            for (int k = 0; k < 6; ++k)
                Dw[(c0 + 8*k)*32 + kx] = make_float2(re[k]*wgt, im[k]*wgt);
        }
        __syncthreads();
        // phase 2: inverse-x DFT (in-register twiddles)
        {
            int xl = t & 127;
            int x  = xh + xl;
            int i0 = (t >> 7) * 24;
            float ang = 6.28318530717958647692f * (float)x / 256.0f;
            float s1, c1; __sincosf(ang, &s1, &c1);
            float twr[32], twi[32];
            twr[0] = 1.0f; twi[0] = 0.0f;
            #pragma unroll
            for (int k = 1; k < 32; ++k) {
                twr[k] = twr[k-1]*c1 - twi[k-1]*s1;
                twi[k] = twr[k-1]*s1 + twi[k-1]*c1;
            }
            for (int i = i0; i < i0 + 24; ++i) {
                const float4* dr4 = (const float4*)(Dw + i*32);
                float acc = 0.0f;
                #pragma unroll
                for (int k4 = 0; k4 < 16; ++k4) {
                    float4 v = dr4[k4];
                    acc += v.x*twr[2*k4]   - v.y*twi[2*k4];
                    acc += v.z*twr[2*k4+1] - v.w*twi[2*k4+1];
                }
                sl[i*128 + xl] = acc;
            }
        }
        __syncthreads();
        int pp = t & 63, og = t >> 6;
        // phase 3: conv1 + gelu -> buf0 (overwrites Dw)
        {
            float acc[12][2];
            #pragma unroll
            for (int oo = 0; oo < 12; ++oo) { float bv = bl[og*12+oo]; acc[oo][0]=bv; acc[oo][1]=bv; }
            for (int i = 0; i < 48; ++i) {
                float2 s = *(const float2*)(sl + i*128 + pp*2);
                const float4* wv = (const float4*)(wl + i*48 + og*12);
                float wq[12];
                *(float4*)(wq+0)=wv[0]; *(float4*)(wq+4)=wv[1]; *(float4*)(wq+8)=wv[2];
                #pragma unroll
                for (int oo = 0; oo < 12; ++oo) { acc[oo][0]+=wq[oo]*s.x; acc[oo][1]+=wq[oo]*s.y; }
            }
            #pragma unroll
            for (int oo = 0; oo < 12; ++oo) {
                int o = og*12+oo;
                float2 g; g.x = gelu_f(acc[oo][0]); g.y = gelu_f(acc[oo][1]);
                *(float2*)(buf0 + o*128 + pp*2) = g;
            }
        }
        __syncthreads();
        for (int idx = t; idx < 2304; idx += 256) {
            int o = idx % 48, i = idx / 48;
            wl[i*48 + o] = w2[o*48 + i];
        }
        if (t < 48) bl[t] = b2[t];
        __syncthreads();
        // phase 4: conv2 + gelu + residual -> UA
        {
            int y2 = blockIdx.x >> 1;
            int xh2 = (blockIdx.x & 1) << 7;
            float acc[12][2];
            #pragma unroll
            for (int oo = 0; oo < 12; ++oo) { float bv = bl[og*12+oo]; acc[oo][0]=bv; acc[oo][1]=bv; }
            for (int i = 0; i < 48; ++i) {
                float2 s = *(const float2*)(buf0 + i*128 + pp*2);
                const float4* wv = (const float4*)(wl + i*48 + og*12);
                float wq[12];
                *(float4*)(wq+0)=wv[0]; *(float4*)(wq+4)=wv[1]; *(float4*)(wq+8)=wv[2];
                #pragma unroll
                for (int oo = 0; oo < 12; ++oo) { acc[oo][0]+=wq[oo]*s.x; acc[oo][1]+=wq[oo]*s.y; }
            }
            #pragma unroll
            for (int oo = 0; oo < 12; ++oo) {
                int o = og*12+oo;
                size_t obase = (size_t)o*NPIXA + (size_t)y2*WA + xh2 + pp*2;
                float2 rv = *(const float2*)(UA + obase);
                float2 r;
                r.x = gelu_f(acc[oo][0]) + rv.x;
                r.y = gelu_f(acc[oo][1]) + rv.y;
                *(float2*)(UA + obase) = r;
            }
        }
    } else {
        // ---- B path: inv_y + inv_x -> SB ----
        int b = blockIdx.x - 512;
        int c = b >> 4, yg = b & 15;
        int kx = t & 31, yr = t >> 5;
        int y = yg * 8 + yr;
        float re = 0.f, im = 0.f;
        const float2* crow = COUT + (size_t)(PA + c) * MM * MM + kx;
        const float2* tab = (const float2*)tiyB;
        #pragma unroll 8
        for (int j = 0; j < 32; ++j) {
            float2 w = crow[j * MM];
            float2 tv = tab[j * HB + y];
            re += w.x*tv.x - w.y*tv.y;
            im += w.x*tv.y + w.y*tv.x;
        }
        float2* ds = (float2*)sm;
        ds[yr*32 + kx] = make_float2(re, im);
        __syncthreads();
        int x = t & 127, rp = t >> 7;
        const float2* txb = (const float2*)tixB;
        for (int rr = rp; rr < 8; rr += 2) {
            const float2* drow = ds + rr*32;
            float a = 0.f;
            #pragma unroll
            for (int k2 = 0; k2 < 32; ++k2) {
                float2 tv = txb[k2*WB + x];
                float2 d = drow[k2];
                a += d.x*tv.x - d.y*tv.y;
            }
            SB[((size_t)c*HB + yg*8 + rr)*WB + x] = a;
        }
    }
}

// ---------------- B-branch 3x3 conv: oc-group 3, 2-deep prefetch ----------------
__global__ __launch_bounds__(256) void k_conv3x3(
        const float* __restrict__ in, float* __restrict__ out,
        const float* __restrict__ w, const float* __restrict__ b,
        const float* resid) {
    __shared__ __attribute__((aligned(16))) float wl[PB*9*4];
    __shared__ float bl[3];
    int o0 = blockIdx.y * 3;
    for (int idx = threadIdx.x; idx < PB*9*3; idx += 256) {
        int oo = idx % 3;
        int r = idx / 3;
        int tap = r % 9;
        int ic = r / 9;
        wl[(ic*9+tap)*4 + oo] = w[((size_t)(o0+oo)*PB + ic)*9 + tap];
    }
    if (threadIdx.x < 3) bl[threadIdx.x] = b[o0+threadIdx.x];
    __syncthreads();

    int wv = threadIdx.x >> 6;
    int lane = threadIdx.x & 63;
    int y = blockIdx.x * 4 + wv;
    int x0 = lane * 2;

    float acc[3][2];
    #pragma unroll
    for (int oo = 0; oo < 3; ++oo) { acc[oo][0]=bl[oo]; acc[oo][1]=bl[oo]; }

    auto loadch = [&](int ic, float2* dst) {
        const float* ip = in + (size_t)ic*NPIXB;
        #pragma unroll
        for (int dy = 0; dy < 3; ++dy) {
            int gy = y - 1 + dy;
            if (gy >= 0 && gy < HB) dst[dy] = *(const float2*)(ip + gy*WB + x0);
            else { dst[dy].x = 0.f; dst[dy].y = 0.f; }
        }
    };
    float win[3][4];
    float2 rnxt[3];
    {
        float2 r0[3];
        loadch(0, r0);
        loadch(1, rnxt);
        #pragma unroll
        for (int dy = 0; dy < 3; ++dy) {
            float lft = __shfl_up(r0[dy].y, 1);  if (lane == 0)  lft = 0.f;
            float rgt = __shfl_down(r0[dy].x, 1); if (lane == 63) rgt = 0.f;
            win[dy][0]=lft; win[dy][1]=r0[dy].x; win[dy][2]=r0[dy].y; win[dy][3]=rgt;
        }
    }
    for (int ic = 0; ic < PB; ++ic) {
        float2 rfut[3];
        if (ic + 2 < PB) loadch(ic + 2, rfut);
        const float* wb_ = wl + ic*36;
        #pragma unroll
        for (int tap = 0; tap < 9; ++tap) {
            int dy = tap / 3, dx = tap % 3;
            float4 w3 = *(const float4*)(wb_ + tap*4);
            float s0 = win[dy][dx];
            float s1 = win[dy][dx+1];
            acc[0][0] += w3.x*s0; acc[0][1] += w3.x*s1;
            acc[1][0] += w3.y*s0; acc[1][1] += w3.y*s1;
            acc[2][0] += w3.z*s0; acc[2][1] += w3.z*s1;
        }
        if (ic + 1 < PB) {
            #pragma unroll
            for (int dy = 0; dy < 3; ++dy) {
                float lft = __shfl_up(rnxt[dy].y, 1);  if (lane == 0)  lft = 0.f;
                float rgt = __shfl_down(rnxt[dy].x, 1); if (lane == 63) rgt = 0.f;
                win[dy][0]=lft; win[dy][1]=rnxt[dy].x; win[dy][2]=rnxt[dy].y; win[dy][3]=rgt;
            }
            rnxt[0]=rfut[0]; rnxt[1]=rfut[1]; rnxt[2]=rfut[2];
        }
    }
    #pragma unroll
    for (int oo = 0; oo < 3; ++oo) {
        size_t obase = (size_t)(o0+oo)*NPIXB + (size_t)y*WB + x0;
        float2 r;
        r.x = gelu_f(acc[oo][0]);
        r.y = gelu_f(acc[oo][1]);
        if (resid) { float2 rv = *(const float2*)(resid+obase); r.x += rv.x; r.y += rv.y; }
        *(float2*)(out+obase) = r;
    }
}

// ---------------- decoder: 48->1 both branches ----------------
__global__ __launch_bounds__(256) void k_decode(
        const float* __restrict__ UA, const float* __restrict__ UB,
        const float* dwa, const float* dba,
        const float* dwb, const float* dbb, float* outp) {
    int t = blockIdx.x*256 + threadIdx.x;
    if (t < NPIXA) {
        float acc = dba[0];
        #pragma unroll 8
        for (int p = 0; p < PA; ++p) acc += dwa[p]*UA[(size_t)p*NPIXA + t];
        outp[t] = acc;
    } else {
        int u = t - NPIXA;
        float acc = dbb[0];
        #pragma unroll 8
        for (int p = 0; p < PB; ++p) acc += dwb[p]*UB[(size_t)p*NPIXB + u];
        outp[t] = acc;
    }
}

extern "C" void kernel_launch(void* const* d_in, const int* in_sizes, int n_in,
                              void* d_out, int out_size, void* d_ws, size_t ws_size,
                              hipStream_t stream) {
    const float* u_a   = (const float*)d_in[0];
    const float* x_a   = (const float*)d_in[1];
    const float* u_b   = (const float*)d_in[2];
    const float* x_b   = (const float*)d_in[3];
    const float* enc_a_w = (const float*)d_in[4];
    const float* enc_a_b = (const float*)d_in[5];
    const float* enc_b_w = (const float*)d_in[6];
    const float* enc_b_b = (const float*)d_in[7];
    const float* dec_a_w = (const float*)d_in[8];
    const float* dec_a_b = (const float*)d_in[9];
    const float* dec_b_w = (const float*)d_in[10];
    const float* dec_b_b = (const float*)d_in[11];
    const float* c1a_w = (const float*)d_in[12];
    const float* c1a_b = (const float*)d_in[13];
    const float* c2a_w = (const float*)d_in[14];
    const float* c2a_b = (const float*)d_in[15];
    const float* c1b_w = (const float*)d_in[16];
    const float* c1b_b = (const float*)d_in[17];
    const float* c2b_w = (const float*)d_in[18];
    const float* c2b_b = (const float*)d_in[19];
    const float* A_re = (const float*)d_in[20];
    const float* A_im = (const float*)d_in[21];

    float* ws = (float*)d_ws;
    size_t off = 0;
    auto alloc = [&](size_t n) { float* p = ws + off; off += n; return p; };
    float* TfxAT = alloc(MM*WA*2);
    float* TfyA  = alloc(MM*HA*2);
    float* TiyA  = alloc(MM*HA*2);
    float* TfxBT = alloc(MM*WB*2);
    float* TfyB  = alloc(MM*HB*2);
    float* TixB  = alloc(MM*WB*2);
    float* TiyB  = alloc(MM*HB*2);
    float* UA = alloc((size_t)PA*NPIXA);
    float* UB = alloc((size_t)PB*NPIXB);
    float* SB = alloc((size_t)PB*NPIXB);
    float* TB = alloc((size_t)PB*NPIXB);
    float2* FA = (float2*)alloc((size_t)PA*HA*MM*2);
    float2* FB = (float2*)alloc((size_t)PB*HB*MM*2);
    float2* CIN  = (float2*)alloc((size_t)PP*MM*MM*2);
    float2* COUT = (float2*)alloc((size_t)PP*MM*MM*2);
    if (off * sizeof(float) > ws_size) return;

    k_pre<<<dim3(48 + 48*320), dim3(256), 0, stream>>>(
        TfxAT,TfyA,TiyA,TfxBT,TfyB,TixB,TiyB,
        u_a,x_a,u_b,x_b, enc_a_w,enc_a_b,enc_b_w,enc_b_b, UA,UB);
    for (int l = 0; l < 4; ++l) {
        k_fwd_x<<<dim3(576), dim3(256), 32*(WA+4)*4, stream>>>(UA,UB,FA,FB,TfxAT,TfxBT);
        k_fwd_y<<<dim3(384), dim3(256), 0, stream>>>(FA,FB,CIN,TfyA,TfyB);
        k_spectral<<<dim3(384), dim3(256), 0, stream>>>(
            A_re + (size_t)l*PP*PP*MM*MM, A_im + (size_t)l*PP*PP*MM*MM, CIN, COUT);
        k_inv<<<dim3(512 + 768), dim3(256), 0, stream>>>(COUT, UA, SB,
            TiyA, TiyB, TixB,
            c1a_w + (size_t)l*PA*PA, c1a_b + (size_t)l*PA,
            c2a_w + (size_t)l*PA*PA, c2a_b + (size_t)l*PA);
        k_conv3x3<<<dim3(32,16), dim3(256), 0, stream>>>(SB, TB,
            c1b_w + (size_t)l*PB*PB*9, c1b_b + (size_t)l*PB, (const float*)nullptr);
        k_conv3x3<<<dim3(32,16), dim3(256), 0, stream>>>(TB, UB,
            c2b_w + (size_t)l*PB*PB*9, c2b_b + (size_t)l*PB, UB);
    }
    k_decode<<<dim3(320), dim3(256), 0, stream>>>(UA, UB,
        dec_a_w, dec_a_b, dec_b_w, dec_b_b, (float*)d_out);
}

// Round 6
// 748.691 us; speedup vs baseline: 1.0087x; 1.0087x over previous
//
#include <hip/hip_runtime.h>

#define HA 256
#define WA 256
#define HB 128
#define WB 128
#define PA 48
#define PB 48
#define PP 96
#define MM 32
#define NPIXA (HA*WA)   // 65536
#define NPIXB (HB*WB)   // 16384

__device__ __forceinline__ float gelu_f(float x) {
    float z = 0.7978845608028654f * (x + 0.044715f * x * x * x);
    float e = __expf(2.0f * z);
    return x - x / (e + 1.0f);
}

// ---------------- tables + encoder fused ----------------
__global__ __launch_bounds__(256) void k_pre(
        float* tfxAT, float* tfyA, float* tiyA, float* tixAT,
        float* tfxBT, float* tfyB, float* tixB, float* tiyB,
        const float* u_a, const float* x_a, const float* u_b, const float* x_b,
        const float* wa, const float* ba, const float* wb, const float* bb,
        float* UA, float* UB) {
    const float TWO_PI = 6.28318530717958647692f;
    int bid = blockIdx.x;
    if (bid < 48) {
        int t = bid * 256 + threadIdx.x;
        if (t < MM * WA) {
            int k = t / WA, x = t - k * WA;
            int m = (k * x) & (WA - 1);
            float ang = TWO_PI * (float)m / (float)WA;
            float s, c; __sincosf(ang, &s, &c);
            float sc = 1.0f / (float)(HA * WA);
            tfxAT[(x*MM + k)*2]   = c * sc;
            tfxAT[(x*MM + k)*2+1] = -s * sc;
            // inverse-x table, transposed [x][k], e^{+i 2pi kx/256}, no weight
            tixAT[(x*MM + k)*2]   = c;
            tixAT[(x*MM + k)*2+1] = s;
            int ky = k - 16;
            int my = (ky * x) & (HA - 1);
            float angy = TWO_PI * (float)my / (float)HA;
            float sy, cy; __sincosf(angy, &sy, &cy);
            tfyA[2*t] = cy; tfyA[2*t+1] = -sy;
            tiyA[2*t] = cy; tiyA[2*t+1] = sy;
        } else if (t < MM * WA + MM * WB) {
            int t2 = t - MM * WA;
            int k = t2 / WB, x = t2 - k * WB;
            int m = (k * x) & (WB - 1);
            float ang = TWO_PI * (float)m / (float)WB;
            float s, c; __sincosf(ang, &s, &c);
            float sc = 1.0f / (float)(HB * WB);
            tfxBT[(x*MM + k)*2]   = c * sc;
            tfxBT[(x*MM + k)*2+1] = -s * sc;
            float wgt = (k == 0) ? 1.0f : 2.0f;
            tixB[2*t2] = wgt * c; tixB[2*t2+1] = wgt * s;
            int ky = k - 16;
            int my = (ky * x) & (HB - 1);
            float angy = TWO_PI * (float)my / (float)HB;
            float sy, cy; __sincosf(angy, &sy, &cy);
            tfyB[2*t2] = cy; tfyB[2*t2+1] = -sy;
            tiyB[2*t2] = cy; tiyB[2*t2+1] = sy;
        }
    } else {
        int eb = bid - 48;
        int o = eb / 320;
        int chunk = eb - o * 320;
        if (chunk < 256) {
            int pix = chunk * 256 + threadIdx.x;
            UA[(size_t)o*NPIXA + pix] = wa[o*3+0]*x_a[pix] + wa[o*3+1]*x_a[NPIXA+pix]
                                      + wa[o*3+2]*u_a[pix] + ba[o];
        } else {
            int pix = (chunk - 256) * 256 + threadIdx.x;
            UB[(size_t)o*NPIXB + pix] = wb[o*3+0]*x_b[pix] + wb[o*3+1]*x_b[NPIXB+pix]
                                      + wb[o*3+2]*u_b[pix] + bb[o];
        }
    }
}

// ---------------- forward DFT along x (R3/R4 version: LDS data + coalesced table) ----------------
__global__ __launch_bounds__(256) void k_fwd_x(
        const float* __restrict__ UA, const float* __restrict__ UB,
        float2* __restrict__ FA, float2* __restrict__ FB,
        const float* __restrict__ tfxAT, const float* __restrict__ tfxBT) {
    extern __shared__ float ls[];
    int bid = blockIdx.x;
    const float* U; float2* F; const float2* tT; int N;
    const int NBA = PA * HA / 32;   // 384
    if (bid < NBA) { U = UA; F = FA; tT = (const float2*)tfxAT; N = WA; }
    else { bid -= NBA; U = UB; F = FB; tT = (const float2*)tfxBT; N = WB; }
    int r0 = bid * 32;
    int tot4 = 32 * N / 4;
    const float4* src = (const float4*)(U + (size_t)r0 * N);
    for (int i = threadIdx.x; i < tot4; i += 256) ((float4*)ls)[i] = src[i];
    __syncthreads();
    int kx = threadIdx.x & 31;
    int rg = (threadIdx.x >> 5) * 4;
    float ar0=0,ai0=0,ar1=0,ai1=0,ar2=0,ai2=0,ar3=0,ai3=0;
    for (int x = 0; x < N; ++x) {
        float2 t = tT[x*MM + kx];
        float u0 = ls[(rg+0)*N + x];
        float u1 = ls[(rg+1)*N + x];
        float u2 = ls[(rg+2)*N + x];
        float u3 = ls[(rg+3)*N + x];
        ar0 += u0*t.x; ai0 += u0*t.y;
        ar1 += u1*t.x; ai1 += u1*t.y;
        ar2 += u2*t.x; ai2 += u2*t.y;
        ar3 += u3*t.x; ai3 += u3*t.y;
    }
    F[(size_t)(r0+rg+0)*MM + kx] = make_float2(ar0, ai0);
    F[(size_t)(r0+rg+1)*MM + kx] = make_float2(ar1, ai1);
    F[(size_t)(r0+rg+2)*MM + kx] = make_float2(ar2, ai2);
    F[(size_t)(r0+rg+3)*MM + kx] = make_float2(ar3, ai3);
}

// ---------------- forward DFT along y ----------------
__global__ __launch_bounds__(256) void k_fwd_y(
        const float2* __restrict__ FA, const float2* __restrict__ FB, float2* CIN,
        const float* __restrict__ tfyA, const float* __restrict__ tfyB) {
    int bid = blockIdx.x;
    const float2* F; const float2* tab; int Ny, pbase;
    if (bid < PA*4) { F = FA; tab = (const float2*)tfyA; Ny = HA; pbase = 0; }
    else { bid -= PA*4; F = FB; tab = (const float2*)tfyB; Ny = HB; pbase = PA; }
    int c = bid >> 2;
    int j = (bid & 3) * 8 + (threadIdx.x >> 5);
    int kx = threadIdx.x & 31;
    float re = 0.f, im = 0.f;
    const float2* fr = F + (size_t)c * Ny * MM + kx;
    const float2* tj = tab + j * Ny;
    #pragma unroll 4
    for (int y = 0; y < Ny; ++y) {
        float2 f = fr[y * MM];
        float2 t = tj[y];
        re += f.x*t.x - f.y*t.y;
        im += f.x*t.y + f.y*t.x;
    }
    CIN[((pbase + c)*MM + j)*MM + kx] = make_float2(re, im);
}

// ---------------- spectral channel mix ----------------
__global__ __launch_bounds__(256) void k_spectral(
        const float* __restrict__ Wre, const float* __restrict__ Wim,
        const float2* __restrict__ CIN, float2* __restrict__ COUT) {
    int t = blockIdx.x * 256 + threadIdx.x;
    int p = t >> 10;
    int mode = t & 1023;
    const float* wr = Wre + (size_t)p * PP * 1024 + mode;
    const float* wi = Wim + (size_t)p * PP * 1024 + mode;
    float re = 0.f, im = 0.f;
    #pragma unroll 8
    for (int q = 0; q < PP; ++q) {
        float a = wr[(size_t)q << 10];
        float b = wi[(size_t)q << 10];
        float2 cv = CIN[(q << 10) + mode];
        re += a*cv.x - b*cv.y;
        im += a*cv.y + b*cv.x;
    }
    COUT[t] = make_float2(re, im);
}

// ---------------- fused inverse ----------------
// A path (blocks 0..511): inv_y -> Dw(LDS) -> inv_x (D in REGISTERS, lane=channel,
// twiddles via wave-uniform global float4 broadcasts) -> conv1x1+gelu x2 + resid -> UA.
// B path (blocks 512..1279): inv_y + inv_x -> SB.
__global__ __launch_bounds__(256) void k_inv(
        const float2* __restrict__ COUT, float* __restrict__ UA,
        float* __restrict__ SB,
        const float* __restrict__ tiyA, const float* __restrict__ tiyB,
        const float* __restrict__ tixB, const float* __restrict__ tixAT,
        const float* __restrict__ w1, const float* __restrict__ b1,
        const float* __restrict__ w2, const float* __restrict__ b2) {
    __shared__ float sm[14896];
    int t = threadIdx.x;
    if (blockIdx.x < 512) {
        float* sl   = sm;                     // [48][130] inv-x output
        float* b0   = sm + 6240;              // [48][130] conv1 output
        float2* Dw  = (float2*)(sm + 6240);   // [48][33] (overlays b0; dead before b0 written)
        float* wl   = sm + 12480;             // 2304 transposed weights
        float* bl   = sm + 14784;             // 48
        float2* tl  = (float2*)(sm + 14832);  // 32 complex tiy row
        int y  = blockIdx.x >> 1;
        int xh = (blockIdx.x & 1) << 7;
        if (t < 32) tl[t] = ((const float2*)tiyA)[t*HA + y];
        for (int idx = t; idx < 2304; idx += 256) {
            int o = idx % 48, i = idx / 48;
            wl[i*48 + o] = w1[o*48 + i];
        }
        if (t < 48) bl[t] = b1[t];
        __syncthreads();
        // phase 0: Dw(c,kx) = sum_j COUT(c,j,kx)*Tiy(j,y), c2r weight folded
        {
            int kx = t & 31, c0 = t >> 5;    // c = c0 + 8k, k=0..5
            float re[6] = {0,0,0,0,0,0}, im[6] = {0,0,0,0,0,0};
            for (int j = 0; j < 32; ++j) {
                float2 ty = tl[j];
                #pragma unroll
                for (int k = 0; k < 6; ++k) {
                    float2 w = COUT[((c0 + 8*k)*32 + j)*32 + kx];
                    re[k] += w.x*ty.x - w.y*ty.y;
                    im[k] += w.x*ty.y + w.y*ty.x;
                }
            }
            float wgt = (kx == 0) ? 1.0f : 2.0f;
            #pragma unroll
            for (int k = 0; k < 6; ++k)
                Dw[(c0 + 8*k)*33 + kx] = make_float2(re[k]*wgt, im[k]*wgt);
        }
        __syncthreads();
        // phase 2: inv-x DFT. lane = channel (48 active), wave w covers x-range of 32.
        {
            int w = t >> 6, lane = t & 63;
            float dwr[32], dwi[32];
            #pragma unroll
            for (int k = 0; k < 32; ++k) { dwr[k] = 0.f; dwi[k] = 0.f; }
            if (lane < 48) {
                const float2* dr = Dw + lane*33;
                #pragma unroll
                for (int k = 0; k < 32; ++k) { float2 v = dr[k]; dwr[k] = v.x; dwi[k] = v.y; }
            }
            int xbase = xh + w*32;
            for (int j = 0; j < 32; ++j) {
                const float4* tw4 = (const float4*)(tixAT + (size_t)(xbase + j) * (MM*2));
                float acc = 0.f;
                #pragma unroll
                for (int k4 = 0; k4 < 16; ++k4) {
                    float4 tv = tw4[k4];
                    acc += dwr[2*k4]*tv.x   - dwi[2*k4]*tv.y;
                    acc += dwr[2*k4+1]*tv.z - dwi[2*k4+1]*tv.w;
                }
                if (lane < 48) sl[lane*130 + w*32 + j] = acc;
            }
        }
        __syncthreads();
        int pp = t & 63, og = t >> 6;
        // phase 3: conv1 + gelu -> b0
        {
            float acc[12][2];
            #pragma unroll
            for (int oo = 0; oo < 12; ++oo) { float bv = bl[og*12+oo]; acc[oo][0]=bv; acc[oo][1]=bv; }
            for (int i = 0; i < 48; ++i) {
                float2 s = *(const float2*)(sl + i*130 + pp*2);
                const float4* wv = (const float4*)(wl + i*48 + og*12);
                float wq[12];
                *(float4*)(wq+0)=wv[0]; *(float4*)(wq+4)=wv[1]; *(float4*)(wq+8)=wv[2];
                #pragma unroll
                for (int oo = 0; oo < 12; ++oo) { acc[oo][0]+=wq[oo]*s.x; acc[oo][1]+=wq[oo]*s.y; }
            }
            __syncthreads();   // ensure all phase-2/3 reads of sl/Dw done before b0 writes
            #pragma unroll
            for (int oo = 0; oo < 12; ++oo) {
                int o = og*12+oo;
                float2 g; g.x = gelu_f(acc[oo][0]); g.y = gelu_f(acc[oo][1]);
                *(float2*)(b0 + o*130 + pp*2) = g;
            }
        }
        __syncthreads();
        for (int idx = t; idx < 2304; idx += 256) {
            int o = idx % 48, i = idx / 48;
            wl[i*48 + o] = w2[o*48 + i];
        }
        if (t < 48) bl[t] = b2[t];
        __syncthreads();
        // phase 4: conv2 + gelu + residual -> UA
        {
            float acc[12][2];
            #pragma unroll
            for (int oo = 0; oo < 12; ++oo) { float bv = bl[og*12+oo]; acc[oo][0]=bv; acc[oo][1]=bv; }
            for (int i = 0; i < 48; ++i) {
                float2 s = *(const float2*)(b0 + i*130 + pp*2);
                const float4* wv = (const float4*)(wl + i*48 + og*12);
                float wq[12];
                *(float4*)(wq+0)=wv[0]; *(float4*)(wq+4)=wv[1]; *(float4*)(wq+8)=wv[2];
                #pragma unroll
                for (int oo = 0; oo < 12; ++oo) { acc[oo][0]+=wq[oo]*s.x; acc[oo][1]+=wq[oo]*s.y; }
            }
            #pragma unroll
            for (int oo = 0; oo < 12; ++oo) {
                int o = og*12+oo;
                size_t obase = (size_t)o*NPIXA + (size_t)y*WA + xh + pp*2;
                float2 rv = *(const float2*)(UA + obase);
                float2 r;
                r.x = gelu_f(acc[oo][0]) + rv.x;
                r.y = gelu_f(acc[oo][1]) + rv.y;
                *(float2*)(UA + obase) = r;
            }
        }
    } else {
        // ---- B path: inv_y + inv_x -> SB ----
        int b = blockIdx.x - 512;
        int c = b >> 4, yg = b & 15;
        int kx = t & 31, yr = t >> 5;
        int y = yg * 8 + yr;
        float re = 0.f, im = 0.f;
        const float2* crow = COUT + (size_t)(PA + c) * MM * MM + kx;
        const float2* tab = (const float2*)tiyB;
        #pragma unroll 8
        for (int j = 0; j < 32; ++j) {
            float2 w = crow[j * MM];
            float2 tv = tab[j * HB + y];
            re += w.x*tv.x - w.y*tv.y;
            im += w.x*tv.y + w.y*tv.x;
        }
        float2* ds = (float2*)sm;
        ds[yr*32 + kx] = make_float2(re, im);
        __syncthreads();
        int x = t & 127, rp = t >> 7;
        const float2* txb = (const float2*)tixB;
        for (int rr = rp; rr < 8; rr += 2) {
            const float2* drow = ds + rr*32;
            float a = 0.f;
            #pragma unroll
            for (int k2 = 0; k2 < 32; ++k2) {
                float2 tv = txb[k2*WB + x];
                float2 d = drow[k2];
                a += d.x*tv.x - d.y*tv.y;
            }
            SB[((size_t)c*HB + yg*8 + rr)*WB + x] = a;
        }
    }
}

// ---------------- B-branch 3x3 conv: oc-group 3, 2-deep prefetch (unchanged) ----------------
__global__ __launch_bounds__(256) void k_conv3x3(
        const float* __restrict__ in, float* __restrict__ out,
        const float* __restrict__ w, const float* __restrict__ b,
        const float* resid) {
    __shared__ __attribute__((aligned(16))) float wl[PB*9*4];
    __shared__ float bl[3];
    int o0 = blockIdx.y * 3;
    for (int idx = threadIdx.x; idx < PB*9*3; idx += 256) {
        int oo = idx % 3;
        int r = idx / 3;
        int tap = r % 9;
        int ic = r / 9;
        wl[(ic*9+tap)*4 + oo] = w[((size_t)(o0+oo)*PB + ic)*9 + tap];
    }
    if (threadIdx.x < 3) bl[threadIdx.x] = b[o0+threadIdx.x];
    __syncthreads();

    int wv = threadIdx.x >> 6;
    int lane = threadIdx.x & 63;
    int y = blockIdx.x * 4 + wv;
    int x0 = lane * 2;

    float acc[3][2];
    #pragma unroll
    for (int oo = 0; oo < 3; ++oo) { acc[oo][0]=bl[oo]; acc[oo][1]=bl[oo]; }

    auto loadch = [&](int ic, float2* dst) {
        const float* ip = in + (size_t)ic*NPIXB;
        #pragma unroll
        for (int dy = 0; dy < 3; ++dy) {
            int gy = y - 1 + dy;
            if (gy >= 0 && gy < HB) dst[dy] = *(const float2*)(ip + gy*WB + x0);
            else { dst[dy].x = 0.f; dst[dy].y = 0.f; }
        }
    };
    float win[3][4];
    float2 rnxt[3];
    {
        float2 r0[3];
        loadch(0, r0);
        loadch(1, rnxt);
        #pragma unroll
        for (int dy = 0; dy < 3; ++dy) {
            float lft = __shfl_up(r0[dy].y, 1);  if (lane == 0)  lft = 0.f;
            float rgt = __shfl_down(r0[dy].x, 1); if (lane == 63) rgt = 0.f;
            win[dy][0]=lft; win[dy][1]=r0[dy].x; win[dy][2]=r0[dy].y; win[dy][3]=rgt;
        }
    }
    for (int ic = 0; ic < PB; ++ic) {
        float2 rfut[3];
        if (ic + 2 < PB) loadch(ic + 2, rfut);
        const float* wb_ = wl + ic*36;
        #pragma unroll
        for (int tap = 0; tap < 9; ++tap) {
            int dy = tap / 3, dx = tap % 3;
            float4 w3 = *(const float4*)(wb_ + tap*4);
            float s0 = win[dy][dx];
            float s1 = win[dy][dx+1];
            acc[0][0] += w3.x*s0; acc[0][1] += w3.x*s1;
            acc[1][0] += w3.y*s0; acc[1][1] += w3.y*s1;
            acc[2][0] += w3.z*s0; acc[2][1] += w3.z*s1;
        }
        if (ic + 1 < PB) {
            #pragma unroll
            for (int dy = 0; dy < 3; ++dy) {
                float lft = __shfl_up(rnxt[dy].y, 1);  if (lane == 0)  lft = 0.f;
                float rgt = __shfl_down(rnxt[dy].x, 1); if (lane == 63) rgt = 0.f;
                win[dy][0]=lft; win[dy][1]=rnxt[dy].x; win[dy][2]=rnxt[dy].y; win[dy][3]=rgt;
            }
            rnxt[0]=rfut[0]; rnxt[1]=rfut[1]; rnxt[2]=rfut[2];
        }
    }
    #pragma unroll
    for (int oo = 0; oo < 3; ++oo) {
        size_t obase = (size_t)(o0+oo)*NPIXB + (size_t)y*WB + x0;
        float2 r;
        r.x = gelu_f(acc[oo][0]);
        r.y = gelu_f(acc[oo][1]);
        if (resid) { float2 rv = *(const float2*)(resid+obase); r.x += rv.x; r.y += rv.y; }
        *(float2*)(out+obase) = r;
    }
}

// ---------------- decoder: 48->1 both branches ----------------
__global__ __launch_bounds__(256) void k_decode(
        const float* __restrict__ UA, const float* __restrict__ UB,
        const float* dwa, const float* dba,
        const float* dwb, const float* dbb, float* outp) {
    int t = blockIdx.x*256 + threadIdx.x;
    if (t < NPIXA) {
        float acc = dba[0];
        #pragma unroll 8
        for (int p = 0; p < PA; ++p) acc += dwa[p]*UA[(size_t)p*NPIXA + t];
        outp[t] = acc;
    } else {
        int u = t - NPIXA;
        float acc = dbb[0];
        #pragma unroll 8
        for (int p = 0; p < PB; ++p) acc += dwb[p]*UB[(size_t)p*NPIXB + u];
        outp[t] = acc;
    }
}

extern "C" void kernel_launch(void* const* d_in, const int* in_sizes, int n_in,
                              void* d_out, int out_size, void* d_ws, size_t ws_size,
                              hipStream_t stream) {
    const float* u_a   = (const float*)d_in[0];
    const float* x_a   = (const float*)d_in[1];
    const float* u_b   = (const float*)d_in[2];
    const float* x_b   = (const float*)d_in[3];
    const float* enc_a_w = (const float*)d_in[4];
    const float* enc_a_b = (const float*)d_in[5];
    const float* enc_b_w = (const float*)d_in[6];
    const float* enc_b_b = (const float*)d_in[7];
    const float* dec_a_w = (const float*)d_in[8];
    const float* dec_a_b = (const float*)d_in[9];
    const float* dec_b_w = (const float*)d_in[10];
    const float* dec_b_b = (const float*)d_in[11];
    const float* c1a_w = (const float*)d_in[12];
    const float* c1a_b = (const float*)d_in[13];
    const float* c2a_w = (const float*)d_in[14];
    const float* c2a_b = (const float*)d_in[15];
    const float* c1b_w = (const float*)d_in[16];
    const float* c1b_b = (const float*)d_in[17];
    const float* c2b_w = (const float*)d_in[18];
    const float* c2b_b = (const float*)d_in[19];
    const float* A_re = (const float*)d_in[20];
    const float* A_im = (const float*)d_in[21];

    float* ws = (float*)d_ws;
    size_t off = 0;
    auto alloc = [&](size_t n) { float* p = ws + off; off += n; return p; };
    float* TfxAT = alloc(MM*WA*2);
    float* TixAT = alloc(MM*WA*2);
    float* TfyA  = alloc(MM*HA*2);
    float* TiyA  = alloc(MM*HA*2);
    float* TfxBT = alloc(MM*WB*2);
    float* TfyB  = alloc(MM*HB*2);
    float* TixB  = alloc(MM*WB*2);
    float* TiyB  = alloc(MM*HB*2);
    float* UA = alloc((size_t)PA*NPIXA);
    float* UB = alloc((size_t)PB*NPIXB);
    float* SB = alloc((size_t)PB*NPIXB);
    float* TB = alloc((size_t)PB*NPIXB);
    float2* FA = (float2*)alloc((size_t)PA*HA*MM*2);
    float2* FB = (float2*)alloc((size_t)PB*HB*MM*2);
    float2* CIN  = (float2*)alloc((size_t)PP*MM*MM*2);
    float2* COUT = (float2*)alloc((size_t)PP*MM*MM*2);
    if (off * sizeof(float) > ws_size) return;

    k_pre<<<dim3(48 + 48*320), dim3(256), 0, stream>>>(
        TfxAT,TfyA,TiyA,TixAT,TfxBT,TfyB,TixB,TiyB,
        u_a,x_a,u_b,x_b, enc_a_w,enc_a_b,enc_b_w,enc_b_b, UA,UB);
    for (int l = 0; l < 4; ++l) {
        k_fwd_x<<<dim3(576), dim3(256), 32768, stream>>>(UA,UB,FA,FB,TfxAT,TfxBT);
        k_fwd_y<<<dim3(384), dim3(256), 0, stream>>>(FA,FB,CIN,TfyA,TfyB);
        k_spectral<<<dim3(384), dim3(256), 0, stream>>>(
            A_re + (size_t)l*PP*PP*MM*MM, A_im + (size_t)l*PP*PP*MM*MM, CIN, COUT);
        k_inv<<<dim3(512 + 768), dim3(256), 0, stream>>>(COUT, UA, SB,
            TiyA, TiyB, TixB, TixAT,
            c1a_w + (size_t)l*PA*PA, c1a_b + (size_t)l*PA,
            c2a_w + (size_t)l*PA*PA, c2a_b + (size_t)l*PA);
        k_conv3x3<<<dim3(32,16), dim3(256), 0, stream>>>(SB, TB,
            c1b_w + (size_t)l*PB*PB*9, c1b_b + (size_t)l*PB, (const float*)nullptr);
        k_conv3x3<<<dim3(32,16), dim3(256), 0, stream>>>(TB, UB,
            c2b_w + (size_t)l*PB*PB*9, c2b_b + (size_t)l*PB, UB);
    }
    k_decode<<<dim3(320), dim3(256), 0, stream>>>(UA, UB,
        dec_a_w, dec_a_b, dec_b_w, dec_b_b, (float*)d_out);
}